// Round 2
// baseline (30407.730 us; speedup 1.0000x reference)
//
#include <hip/hip_runtime.h>

// ---------------------------------------------------------------------------
// 3-layer LayerNorm-GRU (haste style), B=32 T=512 IN=128 H=1024 OUT=80
// Round 2: bf16 -> fp16 everywhere (11-bit mantissa cuts each quantization
// injection 8x; same MFMA rate/geometry/traffic on gfx950).
//   per layer: bulk wx = LN(x@W)*gw  (fp16 MFMA GEMM + in-place LN pass)
//              then 512 sequential steps on a 128-block grid with custom
//              device-wide barriers (2/step), R-slice resident in LDS.
//   final: out = tanh(hs2 @ Wlin + blin)
// ---------------------------------------------------------------------------

typedef float    f32x4 __attribute__((ext_vector_type(4)));
typedef _Float16 f16x8 __attribute__((ext_vector_type(8)));

#define HH      1024
#define TT      512
#define BBATCH  32
#define H3      3072
#define MROWS   16384      // B*T
#define NBLK_R  128
#define HPB     8          // h-indices per recurrence block
#define COLS    24         // 3*HPB columns of R per block
#define LN_EPS  1e-5f

// workspace layout (bytes)
#define OFF_CTRL   0u                 // barrier counters
#define OFF_GSTATS 4096u              // 4 slots * 8 buckets * 32 rows * 2 stats * f32 = 8 KB
#define OFF_H      16384u             // h fp16 [32][1024]       = 64 KB
#define OFF_HF     81920u             // h fp32 [32][1024]       = 128 KB
#define CTRL_BYTES 262144u            // memset region
#define OFF_WLB    262144u            // Wlin^T fp16 [80][1024]  = 160 KB
#define OFF_WB     524288u            // W^T fp16 [3072][K<=1024] = 6 MB
#define OFF_XBF    (8ull<<20)         // x fp16 [16384][128]     = 4 MB
#define OFF_WX     (16ull<<20)        // wx fp16 [16384][3072]   = 96 MB
#define OFF_HSA    (112ull<<20)       // hs fp16 [16384][1024]   = 32 MB
#define OFF_HSB    (144ull<<20)       // hs fp16 [16384][1024]   = 32 MB  (end 176 MB)

// sense-reversing device-wide barrier. bars[0]=count, bars[32]=generation.
__device__ __forceinline__ void gbar(unsigned* bars, unsigned nblk) {
  __syncthreads();
  if (threadIdx.x == 0) {
    const unsigned g = __hip_atomic_load(&bars[32], __ATOMIC_RELAXED, __HIP_MEMORY_SCOPE_AGENT);
    const unsigned p = __hip_atomic_fetch_add(&bars[0], 1u, __ATOMIC_ACQ_REL, __HIP_MEMORY_SCOPE_AGENT);
    if (p == nblk - 1u) {
      __hip_atomic_store(&bars[0], 0u, __ATOMIC_RELAXED, __HIP_MEMORY_SCOPE_AGENT);
      __hip_atomic_store(&bars[32], g + 1u, __ATOMIC_RELEASE, __HIP_MEMORY_SCOPE_AGENT);
    } else {
      int spins = 0;
      while (__hip_atomic_load(&bars[32], __ATOMIC_RELAXED, __HIP_MEMORY_SCOPE_AGENT) == g) {
        __builtin_amdgcn_s_sleep(1);
        if (++spins > (1 << 28)) break;   // safety: wrong answer instead of hang
      }
    }
    __threadfence();   // acquire/release at agent scope
  }
  __syncthreads();
}

// ---------------------------------------------------------------------------
// init: x fp32 -> fp16 ; Wlin [1024][80] -> Wlb^T fp16 [80][1024]
__global__ __launch_bounds__(256, 1) void k_init(
    const float* __restrict__ x, _Float16* __restrict__ xb,
    const float* __restrict__ Wlin, _Float16* __restrict__ Wlb)
{
  const size_t stride = (size_t)gridDim.x * 256;
  for (size_t i = (size_t)blockIdx.x * 256 + threadIdx.x; i < (size_t)MROWS * 128; i += stride)
    xb[i] = (_Float16)x[i];
  for (size_t i = (size_t)blockIdx.x * 256 + threadIdx.x; i < 80u * 1024u; i += stride) {
    const size_t n = i >> 10, k = i & 1023u;
    Wlb[i] = (_Float16)Wlin[k * 80 + n];
  }
}

// W fp32 [K][3072] -> Wb fp16 [3072][K] (n-major for B-fragments)
__global__ __launch_bounds__(256, 1) void k_convW(
    const float* __restrict__ W, _Float16* __restrict__ Wb, const int K)
{
  const int n = blockIdx.x;
  for (int k = threadIdx.x; k < K; k += 256)
    Wb[(size_t)n * K + k] = (_Float16)W[(size_t)k * H3 + n];
}

// Cw[16384][3072] (fp16, raw pre-LN) = A[16384][K] @ W[K][3072]
__global__ __launch_bounds__(256, 1) void k_gemm(
    const _Float16* __restrict__ A,
    const _Float16* __restrict__ Bw,   // [3072][K]
    _Float16* __restrict__ Cw,
    const int K)
{
  __shared__ _Float16 Bs[64][40];
  const int tid = threadIdx.x;
  const int lane = tid & 63, wv = tid >> 6;
  const int l15 = lane & 15, quad = lane >> 4;
  const int tilem = blockIdx.x / 48, tilen = blockIdx.x % 48;
  const int mbase = tilem * 64 + wv * 16;
  const size_t nbase = (size_t)tilen * 64;
  f32x4 acc[4] = {{0.f,0.f,0.f,0.f},{0.f,0.f,0.f,0.f},{0.f,0.f,0.f,0.f},{0.f,0.f,0.f,0.f}};
  const _Float16* arow = A + (size_t)(mbase + l15) * K + quad * 8;
  const int sn = tid >> 2, sk = (tid & 3) * 8;
  const _Float16* bsrc = Bw + (nbase + sn) * K + sk;
  for (int kc = 0; kc < K; kc += 32) {
    __syncthreads();
    *(f16x8*)(&Bs[sn][sk]) = *(const f16x8*)(bsrc + kc);
    __syncthreads();
    const f16x8 af = *(const f16x8*)(arow + kc);
#pragma unroll
    for (int nt = 0; nt < 4; ++nt) {
      const f16x8 bv = *(const f16x8*)(&Bs[nt * 16 + l15][quad * 8]);
      acc[nt] = __builtin_amdgcn_mfma_f32_16x16x32_f16(af, bv, acc[nt], 0, 0, 0);
    }
  }
#pragma unroll
  for (int nt = 0; nt < 4; ++nt)
#pragma unroll
    for (int j = 0; j < 4; ++j)
      Cw[(size_t)(mbase + quad * 4 + j) * H3 + nbase + nt * 16 + l15] = (_Float16)acc[nt][j];
}

// in-place LayerNorm * gw over rows of wx (3072 cols), one row per wave
__global__ __launch_bounds__(256, 1) void k_ln(
    _Float16* __restrict__ wxp, const float* __restrict__ gw)
{
  const int wv = threadIdx.x >> 6, lane = threadIdx.x & 63;
  const size_t row = (size_t)blockIdx.x * 4 + wv;
  _Float16* p = wxp + row * H3 + lane * 8;
  float vals[48];
  float s = 0.f, q = 0.f;
#pragma unroll
  for (int c = 0; c < 6; ++c) {
    const f16x8 v = *(const f16x8*)(p + c * 512);
#pragma unroll
    for (int j = 0; j < 8; ++j) {
      const float f = (float)v[j];
      vals[c * 8 + j] = f; s += f; q += f * f;
    }
  }
#pragma unroll
  for (int m = 1; m < 64; m <<= 1) { s += __shfl_xor(s, m); q += __shfl_xor(q, m); }
  const float mean = s * (1.f / H3);
  const float var  = q * (1.f / H3) - mean * mean;
  const float inv  = rsqrtf(var + LN_EPS);
#pragma unroll
  for (int c = 0; c < 6; ++c) {
    f16x8 o;
#pragma unroll
    for (int j = 0; j < 8; ++j)
      o[j] = (_Float16)((vals[c * 8 + j] - mean) * inv * gw[c * 512 + lane * 8 + j]);
    *(f16x8*)(p + c * 512) = o;
  }
}

// ---------------------------------------------------------------------------
// recurrence: 512 steps, 128 blocks, 2 device barriers per step
__global__ __launch_bounds__(256, 1) void k_recur(
    const float* __restrict__ R, const float* __restrict__ bx,
    const float* __restrict__ br, const float* __restrict__ gr,
    const _Float16* __restrict__ wx,
    _Float16* __restrict__ hs_out,
    _Float16* __restrict__ hglob,
    float* __restrict__ hf32,
    float* __restrict__ gstats,
    unsigned* __restrict__ bars)
{
  __shared__ _Float16 Rs[COLS][HH + 8];   // +8 pad
  __shared__ float rhbuf[BBATCH][COLS];
  __shared__ float statbuf[BBATCH][2][2];
  __shared__ float statfin[BBATCH][2];

  const int tid  = threadIdx.x;
  const int blk  = blockIdx.x;
  const int lane = tid & 63;
  const int wv   = tid >> 6;
  const int mhalf = wv >> 1;      // which 16 batch rows
  const int ntile = wv & 1;       // which 16-col tile of the 24 cols
  const int l15  = lane & 15;
  const int quad = lane >> 4;

  // load R slice (cols {i, H+i, 2H+i} for i in [blk*8, blk*8+8)), fp32->fp16
  for (int n = 0; n < COLS; ++n) {
    const int gc = (n >> 3) * HH + blk * HPB + (n & 7);
    for (int k = tid; k < HH; k += 256)
      Rs[n][k] = (_Float16)R[(size_t)k * H3 + gc];
  }

  // per-thread gate ownership: (batch row, h-index)
  const int b_row = tid >> 3;
  const int jj    = tid & 7;
  const int gi    = blk * HPB + jj;
  const float bxz = bx[gi], bxr = bx[HH + gi], bxg = bx[2 * HH + gi];
  const float brz = br[gi], brr = br[HH + gi], brg = br[2 * HH + gi];
  const float grz = gr[gi], grr = gr[HH + gi], grg = gr[2 * HH + gi];
  float hloc = hf32[b_row * HH + gi];

  if (blk == 0)
    for (int i = tid; i < 4 * 8 * BBATCH * 2; i += 256) gstats[i] = 0.f;

  gbar(bars, NBLK_R);

  const _Float16* hrow = hglob + (size_t)(mhalf * 16 + l15) * HH + quad * 8;
  int nloc = ntile * 16 + l15; if (nloc >= COLS) nloc = COLS - 1;   // clamp pad lanes
  const bool valid = (ntile == 0) | (l15 < 8);

  for (int t = 0; t < TT; ++t) {
    // ---- phase 1: rh_pre chunk = h @ Rslice (M=32 via 2 waves, N=24 via 2 tiles)
    f32x4 acc0 = {0.f,0.f,0.f,0.f}, acc1 = {0.f,0.f,0.f,0.f};
#pragma unroll
    for (int ks = 0; ks < 32; ks += 2) {
      const f16x8 a0 = *(const f16x8*)(hrow + ks * 32);
      const f16x8 b0 = *(const f16x8*)(&Rs[nloc][ks * 32 + quad * 8]);
      acc0 = __builtin_amdgcn_mfma_f32_16x16x32_f16(a0, b0, acc0, 0, 0, 0);
      const f16x8 a1 = *(const f16x8*)(hrow + ks * 32 + 32);
      const f16x8 b1 = *(const f16x8*)(&Rs[nloc][ks * 32 + 32 + quad * 8]);
      acc1 = __builtin_amdgcn_mfma_f32_16x16x32_f16(a1, b1, acc1, 0, 0, 0);
    }
    const f32x4 c = acc0 + acc1;

    // per-row partial LN stats over this block's 24 cols + stash rh values
#pragma unroll
    for (int j = 0; j < 4; ++j) {
      const float v = valid ? c[j] : 0.f;
      if (valid) rhbuf[mhalf * 16 + quad * 4 + j][ntile * 16 + l15] = v;
      float s = v, q = v * v;
      s += __shfl_xor(s, 1); q += __shfl_xor(q, 1);
      s += __shfl_xor(s, 2); q += __shfl_xor(q, 2);
      s += __shfl_xor(s, 4); q += __shfl_xor(q, 4);
      s += __shfl_xor(s, 8); q += __shfl_xor(q, 8);
      if (l15 == 0) {
        statbuf[mhalf * 16 + quad * 4 + j][ntile][0] = s;
        statbuf[mhalf * 16 + quad * 4 + j][ntile][1] = q;
      }
    }
    __syncthreads();
    if (tid < 64) {
      const int row = tid >> 1, st = tid & 1;
      const float v = statbuf[row][0][st] + statbuf[row][1][st];
      unsafeAtomicAdd(&gstats[(((t & 3) * 8 + (blk & 7)) * BBATCH + row) * 2 + st], v);
    }
    // prefetch phase-2 operands before the barrier (wx is static, rhbuf is local)
    const float rzraw = rhbuf[b_row][jj];
    const float rrraw = rhbuf[b_row][8 + jj];
    const float rgraw = rhbuf[b_row][16 + jj];
    const _Float16* wrow = wx + (size_t)(b_row * TT + t) * H3;
    const float wz = (float)wrow[gi];
    const float wr = (float)wrow[HH + gi];
    const float wg = (float)wrow[2 * HH + gi];

    gbar(bars, NBLK_R);   // barrier A: stats complete

    // ---- phase 2: finalize LN, gates, h update
    const int slot = t & 3;
    if (tid < 64) {
      const int row = tid >> 1, st = tid & 1;
      float v = 0.f;
#pragma unroll
      for (int bkt = 0; bkt < 8; ++bkt)
        v += gstats[((slot * 8 + bkt) * BBATCH + row) * 2 + st];
      statfin[row][st] = v;
    }
    __syncthreads();
    const float mean = statfin[b_row][0] * (1.f / H3);
    const float var  = statfin[b_row][1] * (1.f / H3) - mean * mean;
    const float inv  = rsqrtf(var + LN_EPS);
    const float rz = (rzraw - mean) * inv * grz;
    const float rr = (rrraw - mean) * inv * grr;
    const float rg = (rgraw - mean) * inv * grg;
    const float zg    = 1.f / (1.f + __expf(-(wz + bxz + rz + brz)));
    const float rgate = 1.f / (1.f + __expf(-(wr + bxr + rr + brr)));
    const float gg    = tanhf(wg + bxg + rgate * (rg + brg));
    const float hn = zg * hloc + (1.f - zg) * gg;
    hloc = hn;
    const _Float16 hb = (_Float16)hn;
    hglob[b_row * HH + gi] = hb;
    hs_out[(size_t)(b_row * TT + t) * HH + gi] = hb;
    // zero the slot that step t+2 will accumulate into (quiescent now)
    if (tid < 64) {
      const int row = tid >> 1, st = tid & 1;
      gstats[((((t + 2) & 3) * 8 + (blk & 7)) * BBATCH + row) * 2 + st] = 0.f;
    }
    gbar(bars, NBLK_R);   // barrier B: h published
  }
  hf32[b_row * HH + gi] = hloc;   // fp32 handoff to next layer
}

// ---------------------------------------------------------------------------
// out[16384][80] = tanh(hs @ Wlin + blin)
__global__ __launch_bounds__(256, 1) void k_proj(
    const _Float16* __restrict__ hs,
    const _Float16* __restrict__ Wlb,   // [80][1024] fp16
    const float* __restrict__ blin,
    float* __restrict__ out)
{
  const int tid = threadIdx.x, lane = tid & 63, wv = tid >> 6;
  const int l15 = lane & 15, quad = lane >> 4;
  const int mbase = blockIdx.x * 64 + wv * 16;
  f32x4 acc[5] = {{0.f,0.f,0.f,0.f},{0.f,0.f,0.f,0.f},{0.f,0.f,0.f,0.f},
                  {0.f,0.f,0.f,0.f},{0.f,0.f,0.f,0.f}};
  const _Float16* arow = hs + (size_t)(mbase + l15) * HH + quad * 8;
  for (int kc = 0; kc < HH; kc += 32) {
    const f16x8 af = *(const f16x8*)(arow + kc);
#pragma unroll
    for (int nt = 0; nt < 5; ++nt) {
      const f16x8 bv = *(const f16x8*)(Wlb + (size_t)(nt * 16 + l15) * HH + kc + quad * 8);
      acc[nt] = __builtin_amdgcn_mfma_f32_16x16x32_f16(af, bv, acc[nt], 0, 0, 0);
    }
  }
#pragma unroll
  for (int nt = 0; nt < 5; ++nt)
#pragma unroll
    for (int j = 0; j < 4; ++j) {
      const int col = nt * 16 + l15;
      out[(size_t)(mbase + quad * 4 + j) * 80 + col] = tanhf(acc[nt][j] + blin[col]);
    }
}

// ---------------------------------------------------------------------------
extern "C" void kernel_launch(void* const* d_in, const int* in_sizes, int n_in,
                              void* d_out, int out_size, void* d_ws, size_t ws_size,
                              hipStream_t stream)
{
  const float* x    = (const float*)d_in[0];
  const float* W0   = (const float*)d_in[1];
  const float* R0   = (const float*)d_in[2];
  const float* bx0  = (const float*)d_in[3];
  const float* br0  = (const float*)d_in[4];
  const float* gw0  = (const float*)d_in[5];
  const float* gr0  = (const float*)d_in[6];
  const float* Wk   = (const float*)d_in[7];
  const float* Rk   = (const float*)d_in[8];
  const float* bxk  = (const float*)d_in[9];
  const float* brk  = (const float*)d_in[10];
  const float* gwk  = (const float*)d_in[11];
  const float* grk  = (const float*)d_in[12];
  const float* Wlin = (const float*)d_in[13];
  const float* blin = (const float*)d_in[14];

  char* ws = (char*)d_ws;
  unsigned*  bars   = (unsigned*)(ws + OFF_CTRL);
  float*     gstats = (float*)(ws + OFF_GSTATS);
  _Float16*  hglob  = (_Float16*)(ws + OFF_H);
  float*     hf32   = (float*)(ws + OFF_HF);
  _Float16*  Wlb    = (_Float16*)(ws + OFF_WLB);
  _Float16*  Wb     = (_Float16*)(ws + OFF_WB);
  _Float16*  xb     = (_Float16*)(ws + OFF_XBF);
  _Float16*  wx     = (_Float16*)(ws + OFF_WX);
  _Float16*  hsA    = (_Float16*)(ws + OFF_HSA);
  _Float16*  hsB    = (_Float16*)(ws + OFF_HSB);

  hipMemsetAsync(d_ws, 0, CTRL_BYTES, stream);   // barriers, stats, h state

  k_init<<<2048, 256, 0, stream>>>(x, xb, Wlin, Wlb);

  for (int l = 0; l < 3; ++l) {
    const int K = l ? HH : 128;
    const float* Wl  = l ? (Wk  + (size_t)(l - 1) * HH * H3) : W0;
    const float* Rl  = l ? (Rk  + (size_t)(l - 1) * HH * H3) : R0;
    const float* bxl = l ? (bxk + (size_t)(l - 1) * H3) : bx0;
    const float* brl = l ? (brk + (size_t)(l - 1) * H3) : br0;
    const float* gwl = l ? (gwk + (size_t)(l - 1) * H3) : gw0;
    const float* grl = l ? (grk + (size_t)(l - 1) * H3) : gr0;
    const _Float16* Ain = (l == 0) ? xb : ((l == 1) ? hsA : hsB);
    _Float16* hs_out = (l == 1) ? hsB : hsA;

    k_convW<<<H3, 256, 0, stream>>>(Wl, Wb, K);
    k_gemm<<<12288, 256, 0, stream>>>(Ain, Wb, wx, K);
    k_ln<<<4096, 256, 0, stream>>>(wx, gwl);
    k_recur<<<NBLK_R, 256, 0, stream>>>(Rl, bxl, brl, grl, wx, hs_out,
                                        hglob, hf32, gstats, bars);
  }
  k_proj<<<256, 256, 0, stream>>>(hsA, Wlb, blin, (float*)d_out);
}